// Round 1
// baseline (801.649 us; speedup 1.0000x reference)
//
#include <hip/hip_runtime.h>
#include <hip/hip_bf16.h>

#define B_   64
#define S_   4096
#define A_   128
#define FDIM_ 512
#define HDIM_ 512

// ---------------------------------------------------------------------------
// K1: proj_hidden[b][a] = sum_h hidden_state[b][h] * W_hidden[a][h]
// grid: B blocks, 128 threads (one per a). hidden_state row staged in LDS.
// ---------------------------------------------------------------------------
__global__ void k_proj_hidden(const float* __restrict__ hs,
                              const float* __restrict__ W,
                              float* __restrict__ ph) {
    int b = blockIdx.x;
    int a = threadIdx.x;
    __shared__ float s_h[HDIM_];
    for (int i = threadIdx.x; i < HDIM_; i += 128) s_h[i] = hs[b * HDIM_ + i];
    __syncthreads();
    const float4* Wr = (const float4*)(W + (size_t)a * HDIM_);
    const float4* Hr = (const float4*)s_h;
    float acc = 0.f;
#pragma unroll 8
    for (int h4 = 0; h4 < HDIM_ / 4; ++h4) {
        float4 w4 = Wr[h4];
        float4 h4v = Hr[h4];
        acc += w4.x * h4v.x + w4.y * h4v.y + w4.z * h4v.z + w4.w * h4v.w;
    }
    ph[b * A_ + a] = acc;
}

// ---------------------------------------------------------------------------
// K2: scores[b][s] = sum_a tanh(proj_image[b][s][a] + ph[b][a]) * w_score[a]
// One wave (64 lanes) per (b,s); lane covers a = 2*lane, 2*lane+1 (float2).
// block = 256 threads = 4 waves. grid = B*S/4.
// ---------------------------------------------------------------------------
__global__ void k_scores(const float* __restrict__ proj,
                         const float* __restrict__ ph,
                         const float* __restrict__ wsc,
                         float* __restrict__ scores) {
    int wave = (int)((blockIdx.x * blockDim.x + threadIdx.x) >> 6);  // (b,s) flat
    int lane = threadIdx.x & 63;
    int b = wave >> 12;  // / S_
    float2 p = ((const float2*)(proj + (size_t)wave * A_))[lane];
    float2 h = ((const float2*)(ph + b * A_))[lane];
    float2 w = ((const float2*)wsc)[lane];
    float v = tanhf(p.x + h.x) * w.x + tanhf(p.y + h.y) * w.y;
#pragma unroll
    for (int m = 32; m; m >>= 1) v += __shfl_xor(v, m, 64);
    if (lane == 0) scores[wave] = v;
}

// ---------------------------------------------------------------------------
// K3: weights[b][:] = softmax(scores[b][:]) over S. One block (256 thr) per b.
// ---------------------------------------------------------------------------
__global__ void k_softmax(const float* __restrict__ scores,
                          float* __restrict__ weights) {
    int b = blockIdx.x;
    const float* sc = scores + (size_t)b * S_;
    float* wout = weights + (size_t)b * S_;
    int tid = threadIdx.x;
    int lane = tid & 63, wv = tid >> 6;
    __shared__ float s_red[4];

    float mx = -1e30f;
    for (int i = tid; i < S_; i += 256) mx = fmaxf(mx, sc[i]);
#pragma unroll
    for (int m = 32; m; m >>= 1) mx = fmaxf(mx, __shfl_xor(mx, m, 64));
    if (lane == 0) s_red[wv] = mx;
    __syncthreads();
    mx = fmaxf(fmaxf(s_red[0], s_red[1]), fmaxf(s_red[2], s_red[3]));
    __syncthreads();

    float sum = 0.f;
    for (int i = tid; i < S_; i += 256) {
        float e = __expf(sc[i] - mx);
        wout[i] = e;
        sum += e;
    }
#pragma unroll
    for (int m = 32; m; m >>= 1) sum += __shfl_xor(sum, m, 64);
    if (lane == 0) s_red[wv] = sum;
    __syncthreads();
    sum = s_red[0] + s_red[1] + s_red[2] + s_red[3];
    float inv = 1.f / sum;
    for (int i = tid; i < S_; i += 256) wout[i] *= inv;
}

// ---------------------------------------------------------------------------
// K4: context[b][d] = sum_s weights[b][s] * feat[b][s][d]
// grid (32 s-chunks, B). block 256: 128 lanes cover d (float4), 2 s-groups.
// Partial sums via atomicAdd into zeroed context.
// ---------------------------------------------------------------------------
__global__ void k_context(const float* __restrict__ feat,
                          const float* __restrict__ weights,
                          float* __restrict__ ctx) {
    const int NCHUNK = 32;
    const int SC = S_ / NCHUNK;  // 128
    int b = blockIdx.y;
    int c = blockIdx.x;
    int tid = threadIdx.x;
    int d4 = (tid & 127) << 2;
    int sg = tid >> 7;  // 0 or 1
    int s0 = c * SC;
    float4 acc = {0.f, 0.f, 0.f, 0.f};
    for (int s = s0 + sg; s < s0 + SC; s += 2) {
        float w = weights[(size_t)b * S_ + s];
        float4 f = *(const float4*)(feat + ((size_t)b * S_ + s) * FDIM_ + d4);
        acc.x += w * f.x;
        acc.y += w * f.y;
        acc.z += w * f.z;
        acc.w += w * f.w;
    }
    float* o = ctx + (size_t)b * FDIM_ + d4;
    atomicAdd(o + 0, acc.x);
    atomicAdd(o + 1, acc.y);
    atomicAdd(o + 2, acc.z);
    atomicAdd(o + 3, acc.w);
}

extern "C" void kernel_launch(void* const* d_in, const int* in_sizes, int n_in,
                              void* d_out, int out_size, void* d_ws, size_t ws_size,
                              hipStream_t stream) {
    const float* proj_image     = (const float*)d_in[0];  // [B,S,A]
    const float* image_features = (const float*)d_in[1];  // [B,S,FDIM]
    const float* hidden_state   = (const float*)d_in[2];  // [B,HDIM]
    const float* W_hidden       = (const float*)d_in[3];  // [A,HDIM]
    const float* w_score        = (const float*)d_in[4];  // [A]

    float* out     = (float*)d_out;
    float* ctx     = out;                 // [B, FDIM] — output 0
    float* weights = out + B_ * FDIM_;    // [B, S]    — output 1

    float* ph     = (float*)d_ws;         // [B, A]
    float* scores = ph + B_ * A_;         // [B, S]

    // context is accumulated via atomics — zero it (d_out is poisoned 0xAA)
    hipMemsetAsync(ctx, 0, (size_t)B_ * FDIM_ * sizeof(float), stream);

    k_proj_hidden<<<B_, 128, 0, stream>>>(hidden_state, W_hidden, ph);
    k_scores<<<(B_ * S_) / 4, 256, 0, stream>>>(proj_image, ph, w_score, scores);
    k_softmax<<<B_, 256, 0, stream>>>(scores, weights);
    dim3 gctx(32, B_);
    k_context<<<gctx, 256, 0, stream>>>(image_features, weights, ctx);
}

// Round 2
// 775.088 us; speedup vs baseline: 1.0343x; 1.0343x over previous
//
#include <hip/hip_runtime.h>
#include <hip/hip_bf16.h>

#define B_    64
#define S_    4096
#define A_    128
#define FDIM_ 512
#define HDIM_ 512

// fast tanh: (e-1)/(e+1), e = exp(2x). |err| ~1e-6, fine vs 1.57e-3 threshold.
__device__ __forceinline__ float fast_tanh(float x) {
    float e = __expf(2.0f * x);              // v_exp_f32
    return (e - 1.0f) * __builtin_amdgcn_rcpf(e + 1.0f);  // v_rcp_f32
}

// ---------------------------------------------------------------------------
// K1: proj_hidden[b][a] = sum_h hidden_state[b][h] * W_hidden[a][h]
// grid: B blocks, 128 threads (one per a). hidden_state row staged in LDS.
// ---------------------------------------------------------------------------
__global__ void k_proj_hidden(const float* __restrict__ hs,
                              const float* __restrict__ W,
                              float* __restrict__ ph) {
    int b = blockIdx.x;
    int a = threadIdx.x;
    __shared__ float s_h[HDIM_];
    for (int i = threadIdx.x; i < HDIM_; i += 128) s_h[i] = hs[b * HDIM_ + i];
    __syncthreads();
    const float4* Wr = (const float4*)(W + (size_t)a * HDIM_);
    const float4* Hr = (const float4*)s_h;
    float acc = 0.f;
#pragma unroll 8
    for (int h4 = 0; h4 < HDIM_ / 4; ++h4) {
        float4 w4 = Wr[h4];
        float4 h4v = Hr[h4];
        acc += w4.x * h4v.x + w4.y * h4v.y + w4.z * h4v.z + w4.w * h4v.w;
    }
    ph[b * A_ + a] = acc;
}

// ---------------------------------------------------------------------------
// K2: scores[b][s] = sum_a tanh(proj_image[b][s][a] + ph[b][a]) * w_score[a]
// 32 lanes per (b,s) row, float4 per lane (16 B/lane, coalesced).
// block = 256 thr = 8 rows. grid = B*S/8.
// ---------------------------------------------------------------------------
__global__ void k_scores(const float* __restrict__ proj,
                         const float* __restrict__ ph,
                         const float* __restrict__ wsc,
                         float* __restrict__ scores) {
    int tid = threadIdx.x;
    int sub = tid & 31;                              // lane within row (0..31)
    int row = (blockIdx.x << 3) | (tid >> 5);        // (b,s) flat
    int b = row >> 12;                               // / S_
    float4 p = ((const float4*)(proj + (size_t)row * A_))[sub];
    float4 h = ((const float4*)(ph + b * A_))[sub];
    float4 w = ((const float4*)wsc)[sub];
    float v = fast_tanh(p.x + h.x) * w.x
            + fast_tanh(p.y + h.y) * w.y
            + fast_tanh(p.z + h.z) * w.z
            + fast_tanh(p.w + h.w) * w.w;
    // reduce across the 32-lane half-group (xor masks < 32 stay in-group)
#pragma unroll
    for (int m = 16; m; m >>= 1) v += __shfl_xor(v, m, 64);
    if (sub == 0) scores[row] = v;
}

// ---------------------------------------------------------------------------
// K3: weights[b][:] = softmax(scores[b][:]). One block (1024 thr) per b;
// each thread holds one float4 of the row in registers — single global pass.
// ---------------------------------------------------------------------------
__global__ void k_softmax(const float* __restrict__ scores,
                          float* __restrict__ weights) {
    int b = blockIdx.x;
    int tid = threadIdx.x;                 // 0..1023
    int lane = tid & 63, wv = tid >> 6;    // 16 waves
    __shared__ float s_red[16];

    float4 v = ((const float4*)(scores + (size_t)b * S_))[tid];

    float mx = fmaxf(fmaxf(v.x, v.y), fmaxf(v.z, v.w));
#pragma unroll
    for (int m = 32; m; m >>= 1) mx = fmaxf(mx, __shfl_xor(mx, m, 64));
    if (lane == 0) s_red[wv] = mx;
    __syncthreads();
    mx = s_red[0];
#pragma unroll
    for (int i = 1; i < 16; ++i) mx = fmaxf(mx, s_red[i]);
    __syncthreads();

    float4 e;
    e.x = __expf(v.x - mx); e.y = __expf(v.y - mx);
    e.z = __expf(v.z - mx); e.w = __expf(v.w - mx);
    float sum = e.x + e.y + e.z + e.w;
#pragma unroll
    for (int m = 32; m; m >>= 1) sum += __shfl_xor(sum, m, 64);
    if (lane == 0) s_red[wv] = sum;
    __syncthreads();
    sum = 0.f;
#pragma unroll
    for (int i = 0; i < 16; ++i) sum += s_red[i];
    float inv = __builtin_amdgcn_rcpf(sum);

    float4 o = {e.x * inv, e.y * inv, e.z * inv, e.w * inv};
    ((float4*)(weights + (size_t)b * S_))[tid] = o;
}

// ---------------------------------------------------------------------------
// K4: context[b][d] = sum_s weights[b][s] * feat[b][s][d]
// grid (32 s-chunks, B). block 256: 128 lanes cover d (float4), 2 s-groups.
// Partial sums via atomicAdd into zeroed context (64 adds/address).
// ---------------------------------------------------------------------------
__global__ void k_context(const float* __restrict__ feat,
                          const float* __restrict__ weights,
                          float* __restrict__ ctx) {
    const int NCHUNK = 32;
    const int SC = S_ / NCHUNK;  // 128
    int b = blockIdx.y;
    int c = blockIdx.x;
    int tid = threadIdx.x;
    int d4 = (tid & 127) << 2;
    int sg = tid >> 7;  // 0 or 1
    int s0 = c * SC;
    float4 acc = {0.f, 0.f, 0.f, 0.f};
    for (int s = s0 + sg; s < s0 + SC; s += 2) {
        float w = weights[(size_t)b * S_ + s];
        float4 f = *(const float4*)(feat + ((size_t)b * S_ + s) * FDIM_ + d4);
        acc.x += w * f.x;
        acc.y += w * f.y;
        acc.z += w * f.z;
        acc.w += w * f.w;
    }
    float* o = ctx + (size_t)b * FDIM_ + d4;
    atomicAdd(o + 0, acc.x);
    atomicAdd(o + 1, acc.y);
    atomicAdd(o + 2, acc.z);
    atomicAdd(o + 3, acc.w);
}

extern "C" void kernel_launch(void* const* d_in, const int* in_sizes, int n_in,
                              void* d_out, int out_size, void* d_ws, size_t ws_size,
                              hipStream_t stream) {
    const float* proj_image     = (const float*)d_in[0];  // [B,S,A]
    const float* image_features = (const float*)d_in[1];  // [B,S,FDIM]
    const float* hidden_state   = (const float*)d_in[2];  // [B,HDIM]
    const float* W_hidden       = (const float*)d_in[3];  // [A,HDIM]
    const float* w_score        = (const float*)d_in[4];  // [A]

    float* out     = (float*)d_out;
    float* ctx     = out;                 // [B, FDIM] — output 0
    float* weights = out + B_ * FDIM_;    // [B, S]    — output 1

    float* ph     = (float*)d_ws;         // [B, A]
    float* scores = ph + B_ * A_;         // [B, S]

    // context is accumulated via atomics — zero it (d_out is poisoned 0xAA)
    hipMemsetAsync(ctx, 0, (size_t)B_ * FDIM_ * sizeof(float), stream);

    k_proj_hidden<<<B_, 128, 0, stream>>>(hidden_state, W_hidden, ph);
    k_scores<<<(B_ * S_) / 8, 256, 0, stream>>>(proj_image, ph, w_score, scores);
    k_softmax<<<B_, 1024, 0, stream>>>(scores, weights);
    dim3 gctx(32, B_);
    k_context<<<gctx, 256, 0, stream>>>(image_features, weights, ctx);
}